// Round 1
// baseline (979.362 us; speedup 1.0000x reference)
//
#include <hip/hip_runtime.h>
#include <hip/hip_bf16.h>

using bf16 = __hip_bfloat16;
typedef short s16x8 __attribute__((ext_vector_type(8)));
typedef float f32x4 __attribute__((ext_vector_type(4)));

#define BSZ   8
#define NN    15135
#define FF    64
#define GG    73
#define HH    256
#define EE    242160
#define K1P   160                 // 137 padded to mult of 32
#define MREAL (BSZ * NN)          // 121080
#define MPAD  (946 * 128)         // 121088
#define HFC   512

// ---------------------------------------------------------------- degree hist
__global__ void k_deg(const int* __restrict__ col, int* __restrict__ cnt, int e) {
    int i = blockIdx.x * blockDim.x + threadIdx.x;
    if (i < e) atomicAdd(&cnt[col[i]], 1);
}

// ------------------------------------------------- scan + norm factors (1 blk)
__global__ void k_scan(const int* __restrict__ cnt, int* __restrict__ offs,
                       int* __restrict__ cursor, float* __restrict__ dis,
                       float* __restrict__ dinv, int n) {
    __shared__ int s[1024];
    int tid = threadIdx.x;
    int carry = 0;
    for (int base = 0; base < n; base += 1024) {
        int i = base + tid;
        int v = (i < n) ? cnt[i] : 0;
        s[tid] = v;
        __syncthreads();
        for (int off = 1; off < 1024; off <<= 1) {
            int t = (tid >= off) ? s[tid - off] : 0;
            __syncthreads();
            s[tid] += t;
            __syncthreads();
        }
        int incl = s[tid];
        if (i < n) {
            int excl = carry + incl - v;
            offs[i] = excl;
            cursor[i] = excl;
            float d = (float)(v + 1);
            dis[i]  = rsqrtf(d);
            dinv[i] = 1.0f / d;
        }
        int tot = s[1023];
        __syncthreads();
        carry += tot;
    }
    if (tid == 0) offs[n] = carry;
}

// ---------------------------------------------------------------- CSR fill
__global__ void k_csr(const int* __restrict__ row, const int* __restrict__ col,
                      int* __restrict__ cursor, const float* __restrict__ dis,
                      int* __restrict__ csr_row, float* __restrict__ csr_norm, int e) {
    int i = blockIdx.x * blockDim.x + threadIdx.x;
    if (i >= e) return;
    int r = row[i], c = col[i];
    int p = atomicAdd(&cursor[c], 1);
    csr_row[p]  = r;
    csr_norm[p] = dis[r] * dis[c];
}

// --------------------------------------------------------- h0 = [x | pe | 0]
__global__ void k_prep_h0(const float* __restrict__ x, const float* __restrict__ gl,
                          bf16* __restrict__ h0) {
    int idx = blockIdx.x * blockDim.x + threadIdx.x;
    if (idx >= MREAL * K1P) return;
    int m = idx / K1P;
    int j = idx - m * K1P;
    float val;
    if (j < FF) val = x[(size_t)m * FF + j];
    else if (j < FF + GG) {
        int n = m % NN;
        val = gl[(size_t)n * GG + (j - FF)];
    } else val = 0.f;
    h0[idx] = __float2bfloat16(val);
}

// ---------------------------------------------- W [K,256] f32 -> WT [256,Kp] bf16
__global__ void k_prep_w(const float* __restrict__ W, bf16* __restrict__ WT,
                         int K, int Kpad) {
    int idx = blockIdx.x * blockDim.x + threadIdx.x;
    if (idx >= 256 * Kpad) return;
    int nn = idx / Kpad, kk = idx - nn * Kpad;
    WT[idx] = __float2bfloat16(kk < K ? W[(size_t)kk * 256 + nn] : 0.f);
}

// ---------------------------------------------------------------- MFMA GEMM
// C_perm[(n*8+b)*256 + col] = sum_k A[(b*NN+n)][k] * WT[col][k]
#define LDA 40
template <int K>
__global__ __launch_bounds__(256)
void k_gemm(const bf16* __restrict__ A, const bf16* __restrict__ BT,
            bf16* __restrict__ C) {
    __shared__ __align__(16) short As[128 * LDA];
    __shared__ __align__(16) short Bs[128 * LDA];
    const int tid  = threadIdx.x;
    const int bm   = blockIdx.x * 128;
    const int bn   = blockIdx.y * 128;
    const int lane = tid & 63, wave = tid >> 6;
    const int wm   = (wave >> 1) * 64, wn = (wave & 1) * 64;
    const int fr   = lane & 15, quad = lane >> 4;
    const int sr   = tid >> 2;           // 0..63
    const int sc   = (tid & 3) * 8;      // 0,8,16,24

    f32x4 acc[4][4] = {};

    for (int k0 = 0; k0 < K; k0 += 32) {
        #pragma unroll
        for (int rr = 0; rr < 128; rr += 64) {
            uint4 av = *(const uint4*)&A[(size_t)(bm + sr + rr) * K + k0 + sc];
            *(uint4*)&As[(sr + rr) * LDA + sc] = av;
            uint4 bv = *(const uint4*)&BT[(size_t)(bn + sr + rr) * K + k0 + sc];
            *(uint4*)&Bs[(sr + rr) * LDA + sc] = bv;
        }
        __syncthreads();
        s16x8 af[4], bfv[4];
        #pragma unroll
        for (int i = 0; i < 4; ++i)
            af[i] = *(const s16x8*)&As[(wm + i * 16 + fr) * LDA + quad * 8];
        #pragma unroll
        for (int j = 0; j < 4; ++j)
            bfv[j] = *(const s16x8*)&Bs[(wn + j * 16 + fr) * LDA + quad * 8];
        #pragma unroll
        for (int i = 0; i < 4; ++i)
            #pragma unroll
            for (int j = 0; j < 4; ++j)
                acc[i][j] = __builtin_amdgcn_mfma_f32_16x16x32_bf16(
                    af[i], bfv[j], acc[i][j], 0, 0, 0);
        __syncthreads();
    }

    // epilogue: store permuted [(n*8+b)][256]
    #pragma unroll
    for (int i = 0; i < 4; ++i) {
        int rbase = bm + wm + i * 16 + quad * 4;
        #pragma unroll
        for (int r = 0; r < 4; ++r) {
            int row = rbase + r;
            if (row >= MREAL) continue;
            int b = row / NN;
            int n = row - b * NN;
            size_t co = ((size_t)n * 8 + b) * 256;
            #pragma unroll
            for (int j = 0; j < 4; ++j) {
                int colx = bn + wn + j * 16 + fr;
                C[co + colx] = __float2bfloat16(acc[i][j][r]);
            }
        }
    }
}

// ------------------------------------------------------- aggregate + elu + fc
// hw is permuted [(n*8+b)][256]; hout is [b*NN+n][256]
__global__ __launch_bounds__(256)
void k_agg(const bf16* __restrict__ hw, bf16* __restrict__ hout,
           const int* __restrict__ offs, const int* __restrict__ csr_row,
           const float* __restrict__ csr_norm, const float* __restrict__ dinv,
           const float* __restrict__ bias, const float* __restrict__ fcW,
           float* __restrict__ g, int writeH) {
    const int v = blockIdx.x;
    const int j = threadIdx.x;
    const int lane = j & 63, wave = j >> 6;
    const int beg = offs[v], end = offs[v + 1];
    const float di = dinv[v];

    float acc[8];
    {
        const bf16* p = hw + (size_t)v * 2048 + j;
        #pragma unroll
        for (int b = 0; b < 8; ++b) acc[b] = di * __bfloat162float(p[b * 256]);
    }
    for (int e = beg; e < end; ++e) {
        int r = csr_row[e];
        float nm = csr_norm[e];
        const bf16* p = hw + (size_t)r * 2048 + j;
        #pragma unroll
        for (int b = 0; b < 8; ++b) acc[b] += nm * __bfloat162float(p[b * 256]);
    }
    float bj = bias[j];
    float fw = fcW[3 * j];
    __shared__ float wsum[4][8];
    #pragma unroll
    for (int b = 0; b < 8; ++b) {
        float hv = acc[b] + bj;
        hv = hv > 0.f ? hv : expm1f(hv);
        if (writeH) hout[((size_t)b * NN + v) * 256 + j] = __float2bfloat16(hv);
        float p = hv * fw;
        #pragma unroll
        for (int off = 32; off; off >>= 1) p += __shfl_down(p, off);
        if (lane == 0) wsum[wave][b] = p;
    }
    __syncthreads();
    if (j < 8) {
        float s = wsum[0][j] + wsum[1][j] + wsum[2][j] + wsum[3][j];
        g[(size_t)j * NN + v] += s;
    }
}

// ------------------------------------------------------------ lin1 partials
#define LCHUNK 512
__global__ __launch_bounds__(256)
void k_lin1(const float* __restrict__ g, const float* __restrict__ fcb,
            const float* __restrict__ W, float* __restrict__ zacc) {
    int o  = blockIdx.x * 256 + threadIdx.x;   // 0..511
    int n0 = blockIdx.y * LCHUNK;
    int n1 = n0 + LCHUNK; if (n1 > NN) n1 = NN;
    float fb = fcb[0];
    float acc[8] = {};
    for (int n = n0; n < n1; ++n) {
        float w = W[(size_t)n * HFC + o];
        #pragma unroll
        for (int b = 0; b < 8; ++b)
            acc[b] += (g[(size_t)b * NN + n] + fb) * w;
    }
    #pragma unroll
    for (int b = 0; b < 8; ++b) atomicAdd(&zacc[b * HFC + o], acc[b]);
}

// --------------------------------------------------- lin2 + log_softmax (tiny)
__global__ __launch_bounds__(512)
void k_final(const float* __restrict__ zacc, const float* __restrict__ l1b,
             const float* __restrict__ W2, const float* __restrict__ l2b,
             float* __restrict__ out) {
    __shared__ float r0[512], r1[512];
    int t = threadIdx.x;
    for (int b = 0; b < 8; ++b) {
        float zv = zacc[b * HFC + t] + l1b[t];
        zv = zv > 0.f ? zv : expm1f(zv);
        r0[t] = zv * W2[t * 2 + 0];
        r1[t] = zv * W2[t * 2 + 1];
        __syncthreads();
        for (int s = 256; s; s >>= 1) {
            if (t < s) { r0[t] += r0[t + s]; r1[t] += r1[t + s]; }
            __syncthreads();
        }
        if (t == 0) {
            float o0 = r0[0] + l2b[0], o1 = r1[0] + l2b[1];
            float m = fmaxf(o0, o1);
            float lse = m + logf(expf(o0 - m) + expf(o1 - m));
            out[b * 2 + 0] = o0 - lse;
            out[b * 2 + 1] = o1 - lse;
        }
        __syncthreads();
    }
}

// ---------------------------------------------------------------- launcher
extern "C" void kernel_launch(void* const* d_in, const int* in_sizes, int n_in,
                              void* d_out, int out_size, void* d_ws, size_t ws_size,
                              hipStream_t stream) {
    const float* x    = (const float*)d_in[0];
    const int*   eidx = (const int*)d_in[2];      // [0..E) = row, [E..2E) = col
    const float* gl   = (const float*)d_in[3];
    const float* W1   = (const float*)d_in[4];
    const float* b1   = (const float*)d_in[5];
    const float* W2   = (const float*)d_in[6];
    const float* b2   = (const float*)d_in[7];
    const float* W3   = (const float*)d_in[8];
    const float* b3   = (const float*)d_in[9];
    const float* fcW  = (const float*)d_in[10];
    const float* fcb  = (const float*)d_in[11];
    const float* l1W  = (const float*)d_in[12];
    const float* l1b  = (const float*)d_in[13];
    const float* l2W  = (const float*)d_in[14];
    const float* l2b  = (const float*)d_in[15];
    float* out = (float*)d_out;

    // workspace carve-up
    size_t off = 0;
    auto alloc = [&](size_t bytes) {
        void* p = (char*)d_ws + off;
        off += (bytes + 255) & ~(size_t)255;
        return p;
    };
    bf16* bufA     = (bf16*)alloc((size_t)MPAD * 256 * 2);
    bf16* bufB     = (bf16*)alloc((size_t)MPAD * 256 * 2);
    bf16* W1T      = (bf16*)alloc(256 * K1P * 2);
    bf16* W2T      = (bf16*)alloc(256 * 256 * 2);
    bf16* W3T      = (bf16*)alloc(256 * 256 * 2);
    int*  deg_cnt  = (int*)alloc(NN * 4);
    int*  offs     = (int*)alloc((NN + 1) * 4);
    int*  cursor   = (int*)alloc(NN * 4);
    float* dis     = (float*)alloc(NN * 4);
    float* dinv    = (float*)alloc(NN * 4);
    int*  csr_row  = (int*)alloc((size_t)EE * 4);
    float* csr_nrm = (float*)alloc((size_t)EE * 4);
    float* g       = (float*)alloc((size_t)BSZ * NN * 4);
    float* zacc    = (float*)alloc(BSZ * HFC * 4);

    hipMemsetAsync(deg_cnt, 0, NN * 4, stream);
    hipMemsetAsync(g, 0, (size_t)BSZ * NN * 4, stream);
    hipMemsetAsync(zacc, 0, BSZ * HFC * 4, stream);

    const int* erow = eidx;
    const int* ecol = eidx + EE;

    k_deg<<<(EE + 255) / 256, 256, 0, stream>>>(ecol, deg_cnt, EE);
    k_scan<<<1, 1024, 0, stream>>>(deg_cnt, offs, cursor, dis, dinv, NN);
    k_csr<<<(EE + 255) / 256, 256, 0, stream>>>(erow, ecol, cursor, dis,
                                                csr_row, csr_nrm, EE);

    k_prep_h0<<<(MREAL * K1P + 255) / 256, 256, 0, stream>>>(x, gl, bufA);
    k_prep_w<<<(256 * K1P + 255) / 256, 256, 0, stream>>>(W1, W1T, FF + GG, K1P);
    k_prep_w<<<(256 * 256 + 255) / 256, 256, 0, stream>>>(W2, W2T, 256, 256);
    k_prep_w<<<(256 * 256 + 255) / 256, 256, 0, stream>>>(W3, W3T, 256, 256);

    dim3 ggrid(MPAD / 128, 2);

    // layer 1
    k_gemm<K1P><<<ggrid, 256, 0, stream>>>(bufA, W1T, bufB);
    k_agg<<<NN, 256, 0, stream>>>(bufB, bufA, offs, csr_row, csr_nrm, dinv,
                                  b1, fcW + 0, g, 1);
    // layer 2
    k_gemm<256><<<ggrid, 256, 0, stream>>>(bufA, W2T, bufB);
    k_agg<<<NN, 256, 0, stream>>>(bufB, bufA, offs, csr_row, csr_nrm, dinv,
                                  b2, fcW + 1, g, 1);
    // layer 3 (h3 not materialized; only fc contribution)
    k_gemm<256><<<ggrid, 256, 0, stream>>>(bufA, W3T, bufB);
    k_agg<<<NN, 256, 0, stream>>>(bufB, bufA, offs, csr_row, csr_nrm, dinv,
                                  b3, fcW + 2, g, 0);

    k_lin1<<<dim3(2, (NN + LCHUNK - 1) / LCHUNK), 256, 0, stream>>>(g, fcb, l1W, zacc);
    k_final<<<1, 512, 0, stream>>>(zacc, l1b, l2W, l2b, out);
}

// Round 2
// 853.006 us; speedup vs baseline: 1.1481x; 1.1481x over previous
//
#include <hip/hip_runtime.h>
#include <hip/hip_bf16.h>

using bf16 = __hip_bfloat16;
typedef short s16x8 __attribute__((ext_vector_type(8)));
typedef float f32x4 __attribute__((ext_vector_type(4)));

#define BSZ   8
#define NN    15135
#define FF    64
#define GG    73
#define HH    256
#define EE    242160
#define K1P   160                 // 137 padded to mult of 32
#define MREAL (BSZ * NN)          // 121080
#define MPAD  (946 * 128)         // 121088
#define HFC   512
#define NCHUNK 64
#define NCHUNKS ((NN + NCHUNK - 1) / NCHUNK)   // 237

__device__ __forceinline__ float b2f(short s) {
    union { unsigned u; float f; } x;
    x.u = ((unsigned)(unsigned short)s) << 16;
    return x.f;
}

// ---------------------------------------------------------------- degree hist
__global__ void k_deg(const int* __restrict__ col, int* __restrict__ cnt, int e) {
    int i = blockIdx.x * blockDim.x + threadIdx.x;
    if (i < e) atomicAdd(&cnt[col[i]], 1);
}

// ------------------------------------------------- scan + norm factors (1 blk)
__global__ __launch_bounds__(1024)
void k_scan(const int* __restrict__ cnt, int* __restrict__ offs,
            int* __restrict__ cursor, float* __restrict__ dis,
            float* __restrict__ dinv, int n) {
    __shared__ int wsums[16];
    __shared__ int stot;
    int tid = threadIdx.x, lane = tid & 63, wid = tid >> 6;
    int carry = 0;
    for (int base = 0; base < n; base += 1024) {
        int i = base + tid;
        int v = (i < n) ? cnt[i] : 0;
        int s = v;
        #pragma unroll
        for (int off = 1; off < 64; off <<= 1) {
            int t = __shfl_up(s, off);
            if (lane >= off) s += t;
        }
        if (lane == 63) wsums[wid] = s;
        __syncthreads();
        if (tid == 0) {
            int run = 0;
            #pragma unroll
            for (int w = 0; w < 16; ++w) { int t = wsums[w]; wsums[w] = run; run += t; }
            stot = run;
        }
        __syncthreads();
        if (i < n) {
            int excl = carry + wsums[wid] + s - v;
            offs[i] = excl;
            cursor[i] = excl;
            float d = (float)(v + 1);
            dis[i]  = rsqrtf(d);
            dinv[i] = 1.0f / d;
        }
        carry += stot;
        __syncthreads();
    }
    if (tid == 0) offs[n] = carry;
}

// ---------------------------------------------------------------- CSR fill
__global__ void k_csr(const int* __restrict__ row, const int* __restrict__ col,
                      int* __restrict__ cursor, const float* __restrict__ dis,
                      int* __restrict__ csr_row, float* __restrict__ csr_norm, int e) {
    int i = blockIdx.x * blockDim.x + threadIdx.x;
    if (i >= e) return;
    int r = row[i], c = col[i];
    int p = atomicAdd(&cursor[c], 1);
    csr_row[p]  = r;
    csr_norm[p] = dis[r] * dis[c];
}

// --------------------------------------------------------- h0 = [x | pe | 0]
// vectorized: one thread = 8 output cols (16 B store)
__global__ void k_prep_h0(const float* __restrict__ x, const float* __restrict__ gl,
                          bf16* __restrict__ h0) {
    int idx = blockIdx.x * blockDim.x + threadIdx.x;
    if (idx >= MREAL * (K1P / 8)) return;
    int m = idx / (K1P / 8);
    int q = idx - m * (K1P / 8);
    int j0 = q * 8;
    int n = m % NN;
    s16x8 o;
    #pragma unroll
    for (int k = 0; k < 8; ++k) {
        int j = j0 + k;
        float val;
        if (j < FF) val = x[(size_t)m * FF + j];
        else if (j < FF + GG) val = gl[(size_t)n * GG + (j - FF)];
        else val = 0.f;
        o[k] = (short)__bfloat16_as_ushort(__float2bfloat16(val));
    }
    *(s16x8*)&h0[(size_t)m * K1P + j0] = o;
}

// ---------------------------------------------- W [K,256] f32 -> WT [256,Kp] bf16
__global__ void k_prep_w(const float* __restrict__ W, bf16* __restrict__ WT,
                         int K, int Kpad) {
    int idx = blockIdx.x * blockDim.x + threadIdx.x;
    if (idx >= 256 * Kpad) return;
    int nn = idx / Kpad, kk = idx - nn * Kpad;
    WT[idx] = __float2bfloat16(kk < K ? W[(size_t)kk * 256 + nn] : 0.f);
}

// ---------------------------------------------------------------- MFMA GEMM
// C_perm[(n*8+b)*256 + col] = sum_k A[(b*NN+n)][k] * WT[col][k]
#define LDA 40
template <int K>
__global__ __launch_bounds__(256)
void k_gemm(const bf16* __restrict__ A, const bf16* __restrict__ BT,
            bf16* __restrict__ C) {
    __shared__ __align__(16) short As[128 * LDA];
    __shared__ __align__(16) short Bs[128 * LDA];
    const int tid  = threadIdx.x;
    const int bm   = blockIdx.x * 128;
    const int bn   = blockIdx.y * 128;
    const int lane = tid & 63, wave = tid >> 6;
    const int wm   = (wave >> 1) * 64, wn = (wave & 1) * 64;
    const int fr   = lane & 15, quad = lane >> 4;
    const int sr   = tid >> 2;           // 0..63
    const int sc   = (tid & 3) * 8;      // 0,8,16,24

    f32x4 acc[4][4] = {};

    for (int k0 = 0; k0 < K; k0 += 32) {
        #pragma unroll
        for (int rr = 0; rr < 128; rr += 64) {
            uint4 av = *(const uint4*)&A[(size_t)(bm + sr + rr) * K + k0 + sc];
            *(uint4*)&As[(sr + rr) * LDA + sc] = av;
            uint4 bv = *(const uint4*)&BT[(size_t)(bn + sr + rr) * K + k0 + sc];
            *(uint4*)&Bs[(sr + rr) * LDA + sc] = bv;
        }
        __syncthreads();
        s16x8 af[4], bfv[4];
        #pragma unroll
        for (int i = 0; i < 4; ++i)
            af[i] = *(const s16x8*)&As[(wm + i * 16 + fr) * LDA + quad * 8];
        #pragma unroll
        for (int j = 0; j < 4; ++j)
            bfv[j] = *(const s16x8*)&Bs[(wn + j * 16 + fr) * LDA + quad * 8];
        #pragma unroll
        for (int i = 0; i < 4; ++i)
            #pragma unroll
            for (int j = 0; j < 4; ++j)
                acc[i][j] = __builtin_amdgcn_mfma_f32_16x16x32_bf16(
                    af[i], bfv[j], acc[i][j], 0, 0, 0);
        __syncthreads();
    }

    // epilogue: store permuted [(n*8+b)][256]
    #pragma unroll
    for (int i = 0; i < 4; ++i) {
        int rbase = bm + wm + i * 16 + quad * 4;
        #pragma unroll
        for (int r = 0; r < 4; ++r) {
            int row = rbase + r;
            if (row >= MREAL) continue;
            int b = row / NN;
            int n = row - b * NN;
            size_t co = ((size_t)n * 8 + b) * 256;
            #pragma unroll
            for (int j = 0; j < 4; ++j) {
                int colx = bn + wn + j * 16 + fr;
                C[co + colx] = __float2bfloat16(acc[i][j][r]);
            }
        }
    }
}

// ------------------------------------------------------- aggregate + elu + fc
// hw permuted [(n*8+b)][256]; hout [b*NN+n][256].
// thread: b = tid>>5, cols [c8, c8+8) with 16 B vector gathers.
__global__ __launch_bounds__(256)
void k_agg(const bf16* __restrict__ hw, bf16* __restrict__ hout,
           const int* __restrict__ offs, const int* __restrict__ csr_row,
           const float* __restrict__ csr_norm, const float* __restrict__ dinv,
           const float* __restrict__ bias, const float* __restrict__ fcW,
           float* __restrict__ g, int writeH) {
    const int v   = blockIdx.x;
    const int tid = threadIdx.x;
    const int b   = tid >> 5;
    const int c8  = (tid & 31) * 8;
    const int beg = offs[v], end = offs[v + 1];
    const float di = dinv[v];

    float acc[8];
    {
        s16x8 hv = *(const s16x8*)&hw[(size_t)v * 2048 + b * 256 + c8];
        #pragma unroll
        for (int k = 0; k < 8; ++k) acc[k] = di * b2f(hv[k]);
    }
    int r_next = 0; float nm_next = 0.f;
    if (beg < end) { r_next = csr_row[beg]; nm_next = csr_norm[beg]; }
    for (int e = beg; e < end; ++e) {
        int r = r_next; float nm = nm_next;
        if (e + 1 < end) { r_next = csr_row[e + 1]; nm_next = csr_norm[e + 1]; }
        s16x8 hv = *(const s16x8*)&hw[(size_t)r * 2048 + b * 256 + c8];
        #pragma unroll
        for (int k = 0; k < 8; ++k) acc[k] += nm * b2f(hv[k]);
    }

    float p = 0.f;
    s16x8 ob;
    #pragma unroll
    for (int k = 0; k < 8; ++k) {
        float hv2 = acc[k] + bias[c8 + k];
        hv2 = hv2 > 0.f ? hv2 : expm1f(hv2);
        ob[k] = (short)__bfloat16_as_ushort(__float2bfloat16(hv2));
        p += hv2 * fcW[3 * (c8 + k)];
    }
    if (writeH)
        *(s16x8*)&hout[((size_t)b * NN + v) * 256 + c8] = ob;

    #pragma unroll
    for (int off = 16; off; off >>= 1) p += __shfl_down(p, off);
    __shared__ float gs[8];
    if ((tid & 31) == 0) gs[b] = p;
    __syncthreads();
    if (tid < 8) g[(size_t)tid * NN + v] += gs[tid];
}

// ------------------------------------------------------------ lin1 partials
// block = 64 nodes, 256 threads (each 2 outputs of 512). zpart[ny][b*512+o].
__global__ __launch_bounds__(256)
void k_lin1(const float* __restrict__ g, const float* __restrict__ fcb,
            const float* __restrict__ W, float* __restrict__ zpart) {
    const int ny = blockIdx.x;
    const int n0 = ny * NCHUNK;
    const int cnt = min(NCHUNK, NN - n0);
    const int tid = threadIdx.x;
    __shared__ float sg[8][NCHUNK];
    float fb = fcb[0];
    for (int idx = tid; idx < 8 * NCHUNK; idx += 256) {
        int b = idx / NCHUNK, nn = idx - b * NCHUNK;
        sg[b][nn] = (nn < cnt) ? (g[(size_t)b * NN + n0 + nn] + fb) : 0.f;
    }
    __syncthreads();
    float2 acc[8] = {};
    for (int nn = 0; nn < cnt; ++nn) {
        float2 w = *(const float2*)&W[(size_t)(n0 + nn) * HFC + tid * 2];
        #pragma unroll
        for (int b = 0; b < 8; ++b) {
            float gv = sg[b][nn];
            acc[b].x += gv * w.x;
            acc[b].y += gv * w.y;
        }
    }
    #pragma unroll
    for (int b = 0; b < 8; ++b)
        *(float2*)&zpart[(size_t)ny * 4096 + b * 512 + tid * 2] = acc[b];
}

__global__ __launch_bounds__(256)
void k_lin1red(const float* __restrict__ zpart, float* __restrict__ zacc) {
    int t = blockIdx.x * 256 + threadIdx.x;   // 0..4095
    float s = 0.f;
    for (int c = 0; c < NCHUNKS; ++c) s += zpart[(size_t)c * 4096 + t];
    zacc[t] = s;
}

// --------------------------------------------------- lin2 + log_softmax (tiny)
__global__ __launch_bounds__(512)
void k_final(const float* __restrict__ zacc, const float* __restrict__ l1b,
             const float* __restrict__ W2, const float* __restrict__ l2b,
             float* __restrict__ out) {
    __shared__ float r0[512], r1[512];
    int t = threadIdx.x;
    for (int b = 0; b < 8; ++b) {
        float zv = zacc[b * HFC + t] + l1b[t];
        zv = zv > 0.f ? zv : expm1f(zv);
        r0[t] = zv * W2[t * 2 + 0];
        r1[t] = zv * W2[t * 2 + 1];
        __syncthreads();
        for (int s = 256; s; s >>= 1) {
            if (t < s) { r0[t] += r0[t + s]; r1[t] += r1[t + s]; }
            __syncthreads();
        }
        if (t == 0) {
            float o0 = r0[0] + l2b[0], o1 = r1[0] + l2b[1];
            float m = fmaxf(o0, o1);
            float lse = m + logf(expf(o0 - m) + expf(o1 - m));
            out[b * 2 + 0] = o0 - lse;
            out[b * 2 + 1] = o1 - lse;
        }
        __syncthreads();
    }
}

// ---------------------------------------------------------------- launcher
extern "C" void kernel_launch(void* const* d_in, const int* in_sizes, int n_in,
                              void* d_out, int out_size, void* d_ws, size_t ws_size,
                              hipStream_t stream) {
    const float* x    = (const float*)d_in[0];
    const int*   eidx = (const int*)d_in[2];      // [0..E) = row, [E..2E) = col
    const float* gl   = (const float*)d_in[3];
    const float* W1   = (const float*)d_in[4];
    const float* b1   = (const float*)d_in[5];
    const float* W2   = (const float*)d_in[6];
    const float* b2   = (const float*)d_in[7];
    const float* W3   = (const float*)d_in[8];
    const float* b3   = (const float*)d_in[9];
    const float* fcW  = (const float*)d_in[10];
    const float* fcb  = (const float*)d_in[11];
    const float* l1W  = (const float*)d_in[12];
    const float* l1b  = (const float*)d_in[13];
    const float* l2W  = (const float*)d_in[14];
    const float* l2b  = (const float*)d_in[15];
    float* out = (float*)d_out;

    // workspace carve-up
    size_t off = 0;
    auto alloc = [&](size_t bytes) {
        void* p = (char*)d_ws + off;
        off += (bytes + 255) & ~(size_t)255;
        return p;
    };
    bf16* bufA     = (bf16*)alloc((size_t)MPAD * 256 * 2);
    bf16* bufB     = (bf16*)alloc((size_t)MPAD * 256 * 2);
    bf16* W1T      = (bf16*)alloc(256 * K1P * 2);
    bf16* W2T      = (bf16*)alloc(256 * 256 * 2);
    bf16* W3T      = (bf16*)alloc(256 * 256 * 2);
    int*  deg_cnt  = (int*)alloc(NN * 4);
    int*  offs     = (int*)alloc((NN + 1) * 4);
    int*  cursor   = (int*)alloc(NN * 4);
    float* dis     = (float*)alloc(NN * 4);
    float* dinv    = (float*)alloc(NN * 4);
    int*  csr_row  = (int*)alloc((size_t)EE * 4);
    float* csr_nrm = (float*)alloc((size_t)EE * 4);
    float* g       = (float*)alloc((size_t)BSZ * NN * 4);

    // zpart/zacc alias bufB: bufB (layer-3 hw) is dead once the last k_agg ran.
    float* zpart = (float*)bufB;                              // 237*4096*4 = 3.9 MB
    float* zacc  = (float*)((char*)bufB + (8 << 20));         // 16 KB

    hipMemsetAsync(deg_cnt, 0, NN * 4, stream);
    hipMemsetAsync(g, 0, (size_t)BSZ * NN * 4, stream);

    const int* erow = eidx;
    const int* ecol = eidx + EE;

    k_deg<<<(EE + 255) / 256, 256, 0, stream>>>(ecol, deg_cnt, EE);
    k_scan<<<1, 1024, 0, stream>>>(deg_cnt, offs, cursor, dis, dinv, NN);
    k_csr<<<(EE + 255) / 256, 256, 0, stream>>>(erow, ecol, cursor, dis,
                                                csr_row, csr_nrm, EE);

    k_prep_h0<<<(MREAL * (K1P / 8) + 255) / 256, 256, 0, stream>>>(x, gl, bufA);
    k_prep_w<<<(256 * K1P + 255) / 256, 256, 0, stream>>>(W1, W1T, FF + GG, K1P);
    k_prep_w<<<(256 * 256 + 255) / 256, 256, 0, stream>>>(W2, W2T, 256, 256);
    k_prep_w<<<(256 * 256 + 255) / 256, 256, 0, stream>>>(W3, W3T, 256, 256);

    dim3 ggrid(MPAD / 128, 2);

    // layer 1
    k_gemm<K1P><<<ggrid, 256, 0, stream>>>(bufA, W1T, bufB);
    k_agg<<<NN, 256, 0, stream>>>(bufB, bufA, offs, csr_row, csr_nrm, dinv,
                                  b1, fcW + 0, g, 1);
    // layer 2
    k_gemm<256><<<ggrid, 256, 0, stream>>>(bufA, W2T, bufB);
    k_agg<<<NN, 256, 0, stream>>>(bufB, bufA, offs, csr_row, csr_nrm, dinv,
                                  b2, fcW + 1, g, 1);
    // layer 3 (h3 not materialized; only fc contribution)
    k_gemm<256><<<ggrid, 256, 0, stream>>>(bufA, W3T, bufB);
    k_agg<<<NN, 256, 0, stream>>>(bufB, bufA, offs, csr_row, csr_nrm, dinv,
                                  b3, fcW + 2, g, 0);

    k_lin1<<<NCHUNKS, 256, 0, stream>>>(g, fcb, l1W, zpart);
    k_lin1red<<<16, 256, 0, stream>>>(zpart, zacc);
    k_final<<<1, 512, 0, stream>>>(zacc, l1b, l2W, l2b, out);
}

// Round 3
// 807.940 us; speedup vs baseline: 1.2122x; 1.0558x over previous
//
#include <hip/hip_runtime.h>
#include <hip/hip_bf16.h>

using bf16 = __hip_bfloat16;
typedef short s16x8 __attribute__((ext_vector_type(8)));
typedef float f32x4 __attribute__((ext_vector_type(4)));
typedef float f32x2 __attribute__((ext_vector_type(2)));

#define BSZ   8
#define NN    15135
#define FF    64
#define GG    73
#define HH    256
#define EE    242160
#define K1P   160                 // 137 padded to mult of 32
#define MREAL (BSZ * NN)          // 121080
#define MPAD  (946 * 128)         // 121088
#define HFC   512
#define NCHUNK 64
#define NCHUNKS ((NN + NCHUNK - 1) / NCHUNK)   // 237
#define SCANB  ((NN + 255) / 256)              // 60
// fp8 pre-scale: hw stored as e4m3(64*v); 1/64 folded into csr_norm & dinv
#define FP8_INV_SCALE 0.015625f

__device__ __forceinline__ float b2f(short s) {
    union { unsigned u; float f; } x;
    x.u = ((unsigned)(unsigned short)s) << 16;
    return x.f;
}

// decode 16 fp8 (e4m3) from a uint4 into f[0..15] via HW cvt
__device__ __forceinline__ void dec16(uint4 q, float* f) {
    f32x2 t;
    t = __builtin_amdgcn_cvt_pk_f32_fp8(q.x, false); f[0]  = t[0]; f[1]  = t[1];
    t = __builtin_amdgcn_cvt_pk_f32_fp8(q.x, true);  f[2]  = t[0]; f[3]  = t[1];
    t = __builtin_amdgcn_cvt_pk_f32_fp8(q.y, false); f[4]  = t[0]; f[5]  = t[1];
    t = __builtin_amdgcn_cvt_pk_f32_fp8(q.y, true);  f[6]  = t[0]; f[7]  = t[1];
    t = __builtin_amdgcn_cvt_pk_f32_fp8(q.z, false); f[8]  = t[0]; f[9]  = t[1];
    t = __builtin_amdgcn_cvt_pk_f32_fp8(q.z, true);  f[10] = t[0]; f[11] = t[1];
    t = __builtin_amdgcn_cvt_pk_f32_fp8(q.w, false); f[12] = t[0]; f[13] = t[1];
    t = __builtin_amdgcn_cvt_pk_f32_fp8(q.w, true);  f[14] = t[0]; f[15] = t[1];
}

__device__ __forceinline__ unsigned char enc8(float v) {
    int p = __builtin_amdgcn_cvt_pk_fp8_f32(v, v, 0, false);
    return (unsigned char)(p & 0xff);
}

// ---------------------------------------------------------------- degree hist
__global__ void k_deg(const int* __restrict__ col, int* __restrict__ cnt, int e) {
    int i = blockIdx.x * blockDim.x + threadIdx.x;
    if (i < e) atomicAdd(&cnt[col[i]], 1);
}

// --------------------------------------------------------- scan phase A
// per-block inclusive scan of cnt -> cursor(tmp), block sums -> bsum
__global__ __launch_bounds__(256)
void k_scanA(const int* __restrict__ cnt, int* __restrict__ cursor,
             int* __restrict__ bsum) {
    __shared__ int ws[4];
    int i = blockIdx.x * 256 + threadIdx.x;
    int tid = threadIdx.x, lane = tid & 63, wid = tid >> 6;
    int v = (i < NN) ? cnt[i] : 0;
    int s = v;
    #pragma unroll
    for (int off = 1; off < 64; off <<= 1) {
        int t = __shfl_up(s, off);
        if (lane >= off) s += t;
    }
    if (lane == 63) ws[wid] = s;
    __syncthreads();
    int pre = 0;
    #pragma unroll
    for (int w = 0; w < 4; ++w) pre += (w < wid) ? ws[w] : 0;
    int incl = pre + s;
    if (i < NN) cursor[i] = incl;
    if (tid == 255) bsum[blockIdx.x] = incl;
}

// --------------------------------------------------------- scan phase B
__global__ __launch_bounds__(64)
void k_scanB(int* __restrict__ bsum, int* __restrict__ offs) {
    int t = threadIdx.x;
    int v = (t < SCANB) ? bsum[t] : 0;
    int s = v;
    #pragma unroll
    for (int off = 1; off < 64; off <<= 1) {
        int x = __shfl_up(s, off);
        if (t >= off) s += x;
    }
    if (t < SCANB) bsum[t] = s - v;      // exclusive
    if (t == 63) offs[NN] = s;           // grand total
}

// --------------------------------------------------------- scan phase C
__global__ __launch_bounds__(256)
void k_scanC(const int* __restrict__ cnt, int* __restrict__ cursor,
             const int* __restrict__ bsum, int* __restrict__ offs,
             float* __restrict__ dis, float* __restrict__ dinv) {
    int i = blockIdx.x * 256 + threadIdx.x;
    if (i >= NN) return;
    int v = cnt[i];
    int excl = cursor[i] - v + bsum[blockIdx.x];
    offs[i] = excl;
    cursor[i] = excl;
    float d = (float)(v + 1);
    dis[i]  = rsqrtf(d);
    dinv[i] = (1.0f / d) * FP8_INV_SCALE;
}

// ---------------------------------------------------------------- CSR fill
__global__ void k_csr(const int* __restrict__ row, const int* __restrict__ col,
                      int* __restrict__ cursor, const float* __restrict__ dis,
                      int* __restrict__ csr_row, float* __restrict__ csr_norm, int e) {
    int i = blockIdx.x * blockDim.x + threadIdx.x;
    if (i >= e) return;
    int r = row[i], c = col[i];
    int p = atomicAdd(&cursor[c], 1);
    csr_row[p]  = r;
    csr_norm[p] = dis[r] * dis[c] * FP8_INV_SCALE;
}

// --------------------------------------------------------- h0 = [x | pe | 0]
__global__ void k_prep_h0(const float* __restrict__ x, const float* __restrict__ gl,
                          bf16* __restrict__ h0) {
    int idx = blockIdx.x * blockDim.x + threadIdx.x;
    if (idx >= MREAL * (K1P / 8)) return;
    int m = idx / (K1P / 8);
    int q = idx - m * (K1P / 8);
    int j0 = q * 8;
    int n = m % NN;
    s16x8 o;
    #pragma unroll
    for (int k = 0; k < 8; ++k) {
        int j = j0 + k;
        float val;
        if (j < FF) val = x[(size_t)m * FF + j];
        else if (j < FF + GG) val = gl[(size_t)n * GG + (j - FF)];
        else val = 0.f;
        o[k] = (short)__bfloat16_as_ushort(__float2bfloat16(val));
    }
    *(s16x8*)&h0[(size_t)m * K1P + j0] = o;
}

// ---------------------------------------------- W [K,256] f32 -> WT [256,Kp] bf16
__global__ void k_prep_w(const float* __restrict__ W, bf16* __restrict__ WT,
                         int K, int Kpad) {
    int idx = blockIdx.x * blockDim.x + threadIdx.x;
    if (idx >= 256 * Kpad) return;
    int nn = idx / Kpad, kk = idx - nn * Kpad;
    WT[idx] = __float2bfloat16(kk < K ? W[(size_t)kk * 256 + nn] : 0.f);
}

// ---------------------------------------------------------------- MFMA GEMM
// C_perm (fp8, x64) [(n*8+b)*256 + col] = 64 * sum_k A[(b*NN+n)][k] * WT[col][k]
#define LDA 40
template <int K>
__global__ __launch_bounds__(256)
void k_gemm(const bf16* __restrict__ A, const bf16* __restrict__ BT,
            unsigned char* __restrict__ C) {
    __shared__ __align__(16) short As[128 * LDA];
    __shared__ __align__(16) short Bs[128 * LDA];
    const int tid  = threadIdx.x;
    const int bm   = blockIdx.x * 128;
    const int bn   = blockIdx.y * 128;
    const int lane = tid & 63, wave = tid >> 6;
    const int wm   = (wave >> 1) * 64, wn = (wave & 1) * 64;
    const int fr   = lane & 15, quad = lane >> 4;
    const int sr   = tid >> 2;           // 0..63
    const int sc   = (tid & 3) * 8;      // 0,8,16,24

    f32x4 acc[4][4] = {};

    for (int k0 = 0; k0 < K; k0 += 32) {
        #pragma unroll
        for (int rr = 0; rr < 128; rr += 64) {
            uint4 av = *(const uint4*)&A[(size_t)(bm + sr + rr) * K + k0 + sc];
            *(uint4*)&As[(sr + rr) * LDA + sc] = av;
            uint4 bv = *(const uint4*)&BT[(size_t)(bn + sr + rr) * K + k0 + sc];
            *(uint4*)&Bs[(sr + rr) * LDA + sc] = bv;
        }
        __syncthreads();
        s16x8 af[4], bfv[4];
        #pragma unroll
        for (int i = 0; i < 4; ++i)
            af[i] = *(const s16x8*)&As[(wm + i * 16 + fr) * LDA + quad * 8];
        #pragma unroll
        for (int j = 0; j < 4; ++j)
            bfv[j] = *(const s16x8*)&Bs[(wn + j * 16 + fr) * LDA + quad * 8];
        #pragma unroll
        for (int i = 0; i < 4; ++i)
            #pragma unroll
            for (int j = 0; j < 4; ++j)
                acc[i][j] = __builtin_amdgcn_mfma_f32_16x16x32_bf16(
                    af[i], bfv[j], acc[i][j], 0, 0, 0);
        __syncthreads();
    }

    // epilogue: store permuted fp8 [(n*8+b)][256], value x64
    #pragma unroll
    for (int i = 0; i < 4; ++i) {
        int rbase = bm + wm + i * 16 + quad * 4;
        #pragma unroll
        for (int r = 0; r < 4; ++r) {
            int row = rbase + r;
            if (row >= MREAL) continue;
            int b = row / NN;
            int n = row - b * NN;
            size_t co = ((size_t)n * 8 + b) * 256;
            #pragma unroll
            for (int j = 0; j < 4; ++j) {
                int colx = bn + wn + j * 16 + fr;
                C[co + colx] = enc8(acc[i][j][r] * 64.f);
            }
        }
    }
}

// ------------------------------------------------------- aggregate + elu + fc
// hw fp8 permuted [(n*8+b)][256] (x64); hout bf16 [b*NN+n][256].
// 128 threads: b = tid>>4, cols [c16, c16+16) -> one 16 B gather per edge.
__global__ __launch_bounds__(128)
void k_agg(const unsigned char* __restrict__ hw, bf16* __restrict__ hout,
           const int* __restrict__ offs, const int* __restrict__ csr_row,
           const float* __restrict__ csr_norm, const float* __restrict__ dinv,
           const float* __restrict__ bias, const float* __restrict__ fcW,
           float* __restrict__ g, int writeH) {
    const int v   = blockIdx.x;
    const int tid = threadIdx.x;
    const int b   = tid >> 4;
    const int c16 = (tid & 15) * 16;
    const int boff = b * 256 + c16;
    const int beg = offs[v], end = offs[v + 1];
    const float di = dinv[v];   // includes 1/64

    float acc[16];
    {
        uint4 q = *(const uint4*)(hw + (size_t)v * 2048 + boff);
        float f[16]; dec16(q, f);
        #pragma unroll
        for (int k = 0; k < 16; ++k) acc[k] = di * f[k];
    }
    int e = beg;
    for (; e + 1 < end; e += 2) {
        int r0 = csr_row[e], r1 = csr_row[e + 1];
        float m0 = csr_norm[e], m1 = csr_norm[e + 1];
        uint4 q0 = *(const uint4*)(hw + (size_t)r0 * 2048 + boff);
        uint4 q1 = *(const uint4*)(hw + (size_t)r1 * 2048 + boff);
        float f0[16], f1[16];
        dec16(q0, f0); dec16(q1, f1);
        #pragma unroll
        for (int k = 0; k < 16; ++k) acc[k] += m0 * f0[k];
        #pragma unroll
        for (int k = 0; k < 16; ++k) acc[k] += m1 * f1[k];
    }
    if (e < end) {
        int r0 = csr_row[e];
        float m0 = csr_norm[e];
        uint4 q0 = *(const uint4*)(hw + (size_t)r0 * 2048 + boff);
        float f0[16]; dec16(q0, f0);
        #pragma unroll
        for (int k = 0; k < 16; ++k) acc[k] += m0 * f0[k];
    }

    float p = 0.f;
    s16x8 ob0, ob1;
    #pragma unroll
    for (int k = 0; k < 16; ++k) {
        float hv = acc[k] + bias[c16 + k];
        hv = hv > 0.f ? hv : expm1f(hv);
        if (k < 8) ob0[k] = (short)__bfloat16_as_ushort(__float2bfloat16(hv));
        else       ob1[k - 8] = (short)__bfloat16_as_ushort(__float2bfloat16(hv));
        p += hv * fcW[3 * (c16 + k)];
    }
    if (writeH) {
        size_t ho = ((size_t)b * NN + v) * 256 + c16;
        *(s16x8*)&hout[ho]     = ob0;
        *(s16x8*)&hout[ho + 8] = ob1;
    }

    #pragma unroll
    for (int off = 8; off; off >>= 1) p += __shfl_xor(p, off, 16);
    __shared__ float gs[8];
    if ((tid & 15) == 0) gs[b] = p;
    __syncthreads();
    if (tid < 8) g[(size_t)tid * NN + v] += gs[tid];
}

// ------------------------------------------------------------ lin1 partials
__global__ __launch_bounds__(256)
void k_lin1(const float* __restrict__ g, const float* __restrict__ fcb,
            const float* __restrict__ W, float* __restrict__ zpart) {
    const int ny = blockIdx.x;
    const int n0 = ny * NCHUNK;
    const int cnt = min(NCHUNK, NN - n0);
    const int tid = threadIdx.x;
    __shared__ float sg[8][NCHUNK];
    float fb = fcb[0];
    for (int idx = tid; idx < 8 * NCHUNK; idx += 256) {
        int b = idx / NCHUNK, nn = idx - b * NCHUNK;
        sg[b][nn] = (nn < cnt) ? (g[(size_t)b * NN + n0 + nn] + fb) : 0.f;
    }
    __syncthreads();
    float2 acc[8] = {};
    for (int nn = 0; nn < cnt; ++nn) {
        float2 w = *(const float2*)&W[(size_t)(n0 + nn) * HFC + tid * 2];
        #pragma unroll
        for (int b = 0; b < 8; ++b) {
            float gv = sg[b][nn];
            acc[b].x += gv * w.x;
            acc[b].y += gv * w.y;
        }
    }
    #pragma unroll
    for (int b = 0; b < 8; ++b)
        *(float2*)&zpart[(size_t)ny * 4096 + b * 512 + tid * 2] = acc[b];
}

__global__ __launch_bounds__(256)
void k_lin1red(const float* __restrict__ zpart, float* __restrict__ zacc) {
    int t = blockIdx.x * 256 + threadIdx.x;   // 0..4095
    float s = 0.f;
    for (int c = 0; c < NCHUNKS; ++c) s += zpart[(size_t)c * 4096 + t];
    zacc[t] = s;
}

// --------------------------------------------------- lin2 + log_softmax (tiny)
__global__ __launch_bounds__(512)
void k_final(const float* __restrict__ zacc, const float* __restrict__ l1b,
             const float* __restrict__ W2, const float* __restrict__ l2b,
             float* __restrict__ out) {
    __shared__ float r0[512], r1[512];
    int t = threadIdx.x;
    for (int b = 0; b < 8; ++b) {
        float zv = zacc[b * HFC + t] + l1b[t];
        zv = zv > 0.f ? zv : expm1f(zv);
        r0[t] = zv * W2[t * 2 + 0];
        r1[t] = zv * W2[t * 2 + 1];
        __syncthreads();
        for (int s = 256; s; s >>= 1) {
            if (t < s) { r0[t] += r0[t + s]; r1[t] += r1[t + s]; }
            __syncthreads();
        }
        if (t == 0) {
            float o0 = r0[0] + l2b[0], o1 = r1[0] + l2b[1];
            float m = fmaxf(o0, o1);
            float lse = m + logf(expf(o0 - m) + expf(o1 - m));
            out[b * 2 + 0] = o0 - lse;
            out[b * 2 + 1] = o1 - lse;
        }
        __syncthreads();
    }
}

// ---------------------------------------------------------------- launcher
extern "C" void kernel_launch(void* const* d_in, const int* in_sizes, int n_in,
                              void* d_out, int out_size, void* d_ws, size_t ws_size,
                              hipStream_t stream) {
    const float* x    = (const float*)d_in[0];
    const int*   eidx = (const int*)d_in[2];      // [0..E) = row, [E..2E) = col
    const float* gl   = (const float*)d_in[3];
    const float* W1   = (const float*)d_in[4];
    const float* b1   = (const float*)d_in[5];
    const float* W2   = (const float*)d_in[6];
    const float* b2   = (const float*)d_in[7];
    const float* W3   = (const float*)d_in[8];
    const float* b3   = (const float*)d_in[9];
    const float* fcW  = (const float*)d_in[10];
    const float* fcb  = (const float*)d_in[11];
    const float* l1W  = (const float*)d_in[12];
    const float* l1b  = (const float*)d_in[13];
    const float* l2W  = (const float*)d_in[14];
    const float* l2b  = (const float*)d_in[15];
    float* out = (float*)d_out;

    size_t off = 0;
    auto alloc = [&](size_t bytes) {
        void* p = (char*)d_ws + off;
        off += (bytes + 255) & ~(size_t)255;
        return p;
    };
    bf16* bufA          = (bf16*)alloc((size_t)MPAD * 256 * 2);          // 62 MB
    unsigned char* bufC = (unsigned char*)alloc((size_t)MPAD * 256);     // 31 MB
    bf16* W1T      = (bf16*)alloc(256 * K1P * 2);
    bf16* W2T      = (bf16*)alloc(256 * 256 * 2);
    bf16* W3T      = (bf16*)alloc(256 * 256 * 2);
    int*  deg_cnt  = (int*)alloc(NN * 4);
    int*  offs     = (int*)alloc((NN + 1) * 4);
    int*  cursor   = (int*)alloc(NN * 4);
    int*  bsum     = (int*)alloc(SCANB * 4);
    float* dis     = (float*)alloc(NN * 4);
    float* dinv    = (float*)alloc(NN * 4);
    int*  csr_row  = (int*)alloc((size_t)EE * 4);
    float* csr_nrm = (float*)alloc((size_t)EE * 4);
    float* g       = (float*)alloc((size_t)BSZ * NN * 4);

    // zpart/zacc alias bufC: dead after the last k_agg
    float* zpart = (float*)bufC;                              // 3.9 MB
    float* zacc  = (float*)(bufC + (8 << 20));                // 16 KB

    hipMemsetAsync(deg_cnt, 0, NN * 4, stream);
    hipMemsetAsync(g, 0, (size_t)BSZ * NN * 4, stream);

    const int* erow = eidx;
    const int* ecol = eidx + EE;

    k_deg<<<(EE + 255) / 256, 256, 0, stream>>>(ecol, deg_cnt, EE);
    k_scanA<<<SCANB, 256, 0, stream>>>(deg_cnt, cursor, bsum);
    k_scanB<<<1, 64, 0, stream>>>(bsum, offs);
    k_scanC<<<SCANB, 256, 0, stream>>>(deg_cnt, cursor, bsum, offs, dis, dinv);
    k_csr<<<(EE + 255) / 256, 256, 0, stream>>>(erow, ecol, cursor, dis,
                                                csr_row, csr_nrm, EE);

    k_prep_h0<<<(MREAL * (K1P / 8) + 255) / 256, 256, 0, stream>>>(x, gl, bufA);
    k_prep_w<<<(256 * K1P + 255) / 256, 256, 0, stream>>>(W1, W1T, FF + GG, K1P);
    k_prep_w<<<(256 * 256 + 255) / 256, 256, 0, stream>>>(W2, W2T, 256, 256);
    k_prep_w<<<(256 * 256 + 255) / 256, 256, 0, stream>>>(W3, W3T, 256, 256);

    dim3 ggrid(MPAD / 128, 2);

    // layer 1
    k_gemm<K1P><<<ggrid, 256, 0, stream>>>(bufA, W1T, bufC);
    k_agg<<<NN, 128, 0, stream>>>(bufC, bufA, offs, csr_row, csr_nrm, dinv,
                                  b1, fcW + 0, g, 1);
    // layer 2
    k_gemm<256><<<ggrid, 256, 0, stream>>>(bufA, W2T, bufC);
    k_agg<<<NN, 128, 0, stream>>>(bufC, bufA, offs, csr_row, csr_nrm, dinv,
                                  b2, fcW + 1, g, 1);
    // layer 3 (h3 not materialized; only fc contribution)
    k_gemm<256><<<ggrid, 256, 0, stream>>>(bufA, W3T, bufC);
    k_agg<<<NN, 128, 0, stream>>>(bufC, bufA, offs, csr_row, csr_nrm, dinv,
                                  b3, fcW + 2, g, 0);

    k_lin1<<<NCHUNKS, 256, 0, stream>>>(g, fcb, l1W, zpart);
    k_lin1red<<<16, 256, 0, stream>>>(zpart, zacc);
    k_final<<<1, 512, 0, stream>>>(zacc, l1b, l2W, l2b, out);
}

// Round 4
// 774.258 us; speedup vs baseline: 1.2649x; 1.0435x over previous
//
#include <hip/hip_runtime.h>
#include <hip/hip_bf16.h>

using bf16 = __hip_bfloat16;
typedef short s16x8 __attribute__((ext_vector_type(8)));
typedef float f32x4 __attribute__((ext_vector_type(4)));
typedef float f32x2 __attribute__((ext_vector_type(2)));

#define BSZ   8
#define NN    15135
#define FF    64
#define GG    73
#define HH    256
#define EE    242160
#define K1P   160                 // 137 padded to mult of 32
#define MREAL (BSZ * NN)          // 121080
#define MPAD  (946 * 128)         // 121088
#define HFC   512
#define NCHUNK 64
#define NCHUNKS ((NN + NCHUNK - 1) / NCHUNK)   // 237
#define SCANB  ((NN + 255) / 256)              // 60
// fp8 pre-scale: hw stored as e4m3(64*v); 1/64 folded into csr_norm & dinv
#define FP8_INV_SCALE 0.015625f

#define GLOAD_LDS16(gp, lp)                                                     \
    __builtin_amdgcn_global_load_lds(                                           \
        (const __attribute__((address_space(1))) void*)(gp),                    \
        (__attribute__((address_space(3))) void*)(lp), 16, 0, 0)

__device__ __forceinline__ float b2f(short s) {
    union { unsigned u; float f; } x;
    x.u = ((unsigned)(unsigned short)s) << 16;
    return x.f;
}

// decode 16 fp8 (e4m3) from a uint4 into f[0..15] via HW cvt
__device__ __forceinline__ void dec16(uint4 q, float* f) {
    f32x2 t;
    t = __builtin_amdgcn_cvt_pk_f32_fp8(q.x, false); f[0]  = t[0]; f[1]  = t[1];
    t = __builtin_amdgcn_cvt_pk_f32_fp8(q.x, true);  f[2]  = t[0]; f[3]  = t[1];
    t = __builtin_amdgcn_cvt_pk_f32_fp8(q.y, false); f[4]  = t[0]; f[5]  = t[1];
    t = __builtin_amdgcn_cvt_pk_f32_fp8(q.y, true);  f[6]  = t[0]; f[7]  = t[1];
    t = __builtin_amdgcn_cvt_pk_f32_fp8(q.z, false); f[8]  = t[0]; f[9]  = t[1];
    t = __builtin_amdgcn_cvt_pk_f32_fp8(q.z, true);  f[10] = t[0]; f[11] = t[1];
    t = __builtin_amdgcn_cvt_pk_f32_fp8(q.w, false); f[12] = t[0]; f[13] = t[1];
    t = __builtin_amdgcn_cvt_pk_f32_fp8(q.w, true);  f[14] = t[0]; f[15] = t[1];
}

__device__ __forceinline__ unsigned char enc8(float v) {
    int p = __builtin_amdgcn_cvt_pk_fp8_f32(v, v, 0, false);
    return (unsigned char)(p & 0xff);
}

// ---------------------------------------------------------------- degree hist
__global__ void k_deg(const int* __restrict__ col, int* __restrict__ cnt, int e) {
    int i = blockIdx.x * blockDim.x + threadIdx.x;
    if (i < e) atomicAdd(&cnt[col[i]], 1);
}

// --------------------------------------------------------- scan phase A
__global__ __launch_bounds__(256)
void k_scanA(const int* __restrict__ cnt, int* __restrict__ cursor,
             int* __restrict__ bsum) {
    __shared__ int ws[4];
    int i = blockIdx.x * 256 + threadIdx.x;
    int tid = threadIdx.x, lane = tid & 63, wid = tid >> 6;
    int v = (i < NN) ? cnt[i] : 0;
    int s = v;
    #pragma unroll
    for (int off = 1; off < 64; off <<= 1) {
        int t = __shfl_up(s, off);
        if (lane >= off) s += t;
    }
    if (lane == 63) ws[wid] = s;
    __syncthreads();
    int pre = 0;
    #pragma unroll
    for (int w = 0; w < 4; ++w) pre += (w < wid) ? ws[w] : 0;
    int incl = pre + s;
    if (i < NN) cursor[i] = incl;
    if (tid == 255) bsum[blockIdx.x] = incl;
}

// --------------------------------------------------------- scan phase B
__global__ __launch_bounds__(64)
void k_scanB(int* __restrict__ bsum, int* __restrict__ offs) {
    int t = threadIdx.x;
    int v = (t < SCANB) ? bsum[t] : 0;
    int s = v;
    #pragma unroll
    for (int off = 1; off < 64; off <<= 1) {
        int x = __shfl_up(s, off);
        if (t >= off) s += x;
    }
    if (t < SCANB) bsum[t] = s - v;      // exclusive
    if (t == 63) offs[NN] = s;           // grand total
}

// --------------------------------------------------------- scan phase C
__global__ __launch_bounds__(256)
void k_scanC(const int* __restrict__ cnt, int* __restrict__ cursor,
             const int* __restrict__ bsum, int* __restrict__ offs,
             float* __restrict__ dis, float* __restrict__ dinv) {
    int i = blockIdx.x * 256 + threadIdx.x;
    if (i >= NN) return;
    int v = cnt[i];
    int excl = cursor[i] - v + bsum[blockIdx.x];
    offs[i] = excl;
    cursor[i] = excl;
    float d = (float)(v + 1);
    dis[i]  = rsqrtf(d);
    dinv[i] = (1.0f / d) * FP8_INV_SCALE;
}

// ---------------------------------------------------------------- CSR fill
__global__ void k_csr(const int* __restrict__ row, const int* __restrict__ col,
                      int* __restrict__ cursor, const float* __restrict__ dis,
                      int* __restrict__ csr_row, float* __restrict__ csr_norm, int e) {
    int i = blockIdx.x * blockDim.x + threadIdx.x;
    if (i >= e) return;
    int r = row[i], c = col[i];
    int p = atomicAdd(&cursor[c], 1);
    csr_row[p]  = r;
    csr_norm[p] = dis[r] * dis[c] * FP8_INV_SCALE;
}

// --------------------------------------------------------- h0 = [x | pe | 0]
__global__ void k_prep_h0(const float* __restrict__ x, const float* __restrict__ gl,
                          bf16* __restrict__ h0) {
    int idx = blockIdx.x * blockDim.x + threadIdx.x;
    if (idx >= MREAL * (K1P / 8)) return;
    int m = idx / (K1P / 8);
    int q = idx - m * (K1P / 8);
    int j0 = q * 8;
    int n = m % NN;
    s16x8 o;
    #pragma unroll
    for (int k = 0; k < 8; ++k) {
        int j = j0 + k;
        float val;
        if (j < FF) val = x[(size_t)m * FF + j];
        else if (j < FF + GG) val = gl[(size_t)n * GG + (j - FF)];
        else val = 0.f;
        o[k] = (short)__bfloat16_as_ushort(__float2bfloat16(val));
    }
    *(s16x8*)&h0[(size_t)m * K1P + j0] = o;
}

// ---------------------------------------------- W [K,256] f32 -> WT [256,Kp] bf16
__global__ void k_prep_w(const float* __restrict__ W, bf16* __restrict__ WT,
                         int K, int Kpad) {
    int idx = blockIdx.x * blockDim.x + threadIdx.x;
    if (idx >= 256 * Kpad) return;
    int nn = idx / Kpad, kk = idx - nn * Kpad;
    WT[idx] = __float2bfloat16(kk < K ? W[(size_t)kk * 256 + nn] : 0.f);
}

// ---------------------------------------------------------------- MFMA GEMM
// m97 structure: global_load_lds width=16, unpadded [128][32] LDS tiles.
// C_perm (fp8, x64) [(n*8+b)*256 + col] = 64 * sum_k A[(b*NN+n)][k] * WT[col][k]
#define BK 32
template <int K>
__global__ __launch_bounds__(256)
void k_gemm(const bf16* __restrict__ A, const bf16* __restrict__ BT,
            unsigned char* __restrict__ C) {
    __shared__ __align__(16) short As[128 * BK];
    __shared__ __align__(16) short Bs[128 * BK];
    const int tid  = threadIdx.x;
    const int bm   = blockIdx.x * 128;
    const int bn   = blockIdx.y * 128;
    const int lane = tid & 63, wave = tid >> 6;
    const int wm   = (wave >> 1) * 64, wn = (wave & 1) * 64;
    const int fr   = lane & 15, quad = lane >> 4;
    const int r    = tid >> 2;           // 0..63
    const int c    = (tid & 3) * 8;      // shorts: 0,8,16,24

    const bf16* Ap0 = A  + (size_t)(bm + r) * K + c;
    const bf16* Ap1 = Ap0 + (size_t)64 * K;
    const bf16* Bp0 = BT + (size_t)(bn + r) * K + c;
    const bf16* Bp1 = Bp0 + (size_t)64 * K;
    short* AsT0 = As + tid * 8;          // byte offset tid*16 (rows 0..63)
    short* AsT1 = As + 2048 + tid * 8;   // rows 64..127
    short* BsT0 = Bs + tid * 8;
    short* BsT1 = Bs + 2048 + tid * 8;

    f32x4 acc[4][4] = {};

    for (int k0 = 0; k0 < K; k0 += BK) {
        GLOAD_LDS16(Ap0 + k0, AsT0);
        GLOAD_LDS16(Ap1 + k0, AsT1);
        GLOAD_LDS16(Bp0 + k0, BsT0);
        GLOAD_LDS16(Bp1 + k0, BsT1);
        __syncthreads();
        s16x8 af[4], bfv[4];
        #pragma unroll
        for (int i = 0; i < 4; ++i)
            af[i] = *(const s16x8*)&As[(wm + i * 16 + fr) * BK + quad * 8];
        #pragma unroll
        for (int j = 0; j < 4; ++j)
            bfv[j] = *(const s16x8*)&Bs[(wn + j * 16 + fr) * BK + quad * 8];
        #pragma unroll
        for (int i = 0; i < 4; ++i)
            #pragma unroll
            for (int j = 0; j < 4; ++j)
                acc[i][j] = __builtin_amdgcn_mfma_f32_16x16x32_bf16(
                    af[i], bfv[j], acc[i][j], 0, 0, 0);
        __syncthreads();
    }

    // epilogue: store permuted fp8 [(n*8+b)][256], value x64
    #pragma unroll
    for (int i = 0; i < 4; ++i) {
        int rbase = bm + wm + i * 16 + quad * 4;
        #pragma unroll
        for (int rr = 0; rr < 4; ++rr) {
            int row = rbase + rr;
            if (row >= MREAL) continue;
            int b = row / NN;
            int n = row - b * NN;
            size_t co = ((size_t)n * 8 + b) * 256;
            #pragma unroll
            for (int j = 0; j < 4; ++j) {
                int colx = bn + wn + j * 16 + fr;
                C[co + colx] = enc8(acc[i][j][rr] * 64.f);
            }
        }
    }
}

// ------------------------------------------------------- aggregate + elu + fc
// hw fp8 permuted [(n*8+b)][256] (x64); hout bf16 [b*NN+n][256].
// 128 threads: b = tid>>4, cols [c16,c16+16). Neighbor list staged in LDS,
// row gathers unrolled x8 for deep MLP (latency-bound fix).
#define ECH 96
__global__ __launch_bounds__(128)
void k_agg(const unsigned char* __restrict__ hw, bf16* __restrict__ hout,
           const int* __restrict__ offs, const int* __restrict__ csr_row,
           const float* __restrict__ csr_norm, const float* __restrict__ dinv,
           const float* __restrict__ bias, const float* __restrict__ fcW,
           float* __restrict__ g, int writeH) {
    const int v   = blockIdx.x;
    const int tid = threadIdx.x;
    const int b   = tid >> 4;
    const int c16 = (tid & 15) * 16;
    const int boff = b * 256 + c16;
    const int beg = offs[v], end = offs[v + 1];
    const float di = dinv[v];   // includes 1/64

    __shared__ int   sIdx[ECH];
    __shared__ float sNrm[ECH];

    float acc[16];
    {
        uint4 q = *(const uint4*)(hw + (size_t)v * 2048 + boff);
        float f[16]; dec16(q, f);
        #pragma unroll
        for (int k = 0; k < 16; ++k) acc[k] = di * f[k];
    }

    for (int base = beg; base < end; base += ECH) {
        int cnt = end - base; if (cnt > ECH) cnt = ECH;
        __syncthreads();
        if (tid < cnt) {
            sIdx[tid] = csr_row[base + tid];
            sNrm[tid] = csr_norm[base + tid];
        }
        __syncthreads();
        int e = 0;
        for (; e + 8 <= cnt; e += 8) {
            uint4 q[8];
            #pragma unroll
            for (int u = 0; u < 8; ++u)
                q[u] = *(const uint4*)(hw + (size_t)sIdx[e + u] * 2048 + boff);
            #pragma unroll
            for (int u = 0; u < 8; ++u) {
                float m = sNrm[e + u];
                float f[16]; dec16(q[u], f);
                #pragma unroll
                for (int k = 0; k < 16; ++k) acc[k] += m * f[k];
            }
        }
        for (; e < cnt; ++e) {
            float m = sNrm[e];
            uint4 q0 = *(const uint4*)(hw + (size_t)sIdx[e] * 2048 + boff);
            float f[16]; dec16(q0, f);
            #pragma unroll
            for (int k = 0; k < 16; ++k) acc[k] += m * f[k];
        }
    }

    float p = 0.f;
    s16x8 ob0, ob1;
    #pragma unroll
    for (int k = 0; k < 16; ++k) {
        float hv = acc[k] + bias[c16 + k];
        hv = hv > 0.f ? hv : expm1f(hv);
        if (k < 8) ob0[k] = (short)__bfloat16_as_ushort(__float2bfloat16(hv));
        else       ob1[k - 8] = (short)__bfloat16_as_ushort(__float2bfloat16(hv));
        p += hv * fcW[3 * (c16 + k)];
    }
    if (writeH) {
        size_t ho = ((size_t)b * NN + v) * 256 + c16;
        *(s16x8*)&hout[ho]     = ob0;
        *(s16x8*)&hout[ho + 8] = ob1;
    }

    #pragma unroll
    for (int off = 8; off; off >>= 1) p += __shfl_xor(p, off, 16);
    __shared__ float gs[8];
    if ((tid & 15) == 0) gs[b] = p;
    __syncthreads();
    if (tid < 8) g[(size_t)tid * NN + v] += gs[tid];
}

// ------------------------------------------------------------ lin1 partials
__global__ __launch_bounds__(256)
void k_lin1(const float* __restrict__ g, const float* __restrict__ fcb,
            const float* __restrict__ W, float* __restrict__ zpart) {
    const int ny = blockIdx.x;
    const int n0 = ny * NCHUNK;
    const int cnt = min(NCHUNK, NN - n0);
    const int tid = threadIdx.x;
    __shared__ float sg[8][NCHUNK];
    float fb = fcb[0];
    for (int idx = tid; idx < 8 * NCHUNK; idx += 256) {
        int b = idx / NCHUNK, nn = idx - b * NCHUNK;
        sg[b][nn] = (nn < cnt) ? (g[(size_t)b * NN + n0 + nn] + fb) : 0.f;
    }
    __syncthreads();
    float2 acc[8] = {};
    for (int nn = 0; nn < cnt; ++nn) {
        float2 w = *(const float2*)&W[(size_t)(n0 + nn) * HFC + tid * 2];
        #pragma unroll
        for (int b = 0; b < 8; ++b) {
            float gv = sg[b][nn];
            acc[b].x += gv * w.x;
            acc[b].y += gv * w.y;
        }
    }
    #pragma unroll
    for (int b = 0; b < 8; ++b)
        *(float2*)&zpart[(size_t)ny * 4096 + b * 512 + tid * 2] = acc[b];
}

__global__ __launch_bounds__(256)
void k_lin1red(const float* __restrict__ zpart, float* __restrict__ zacc) {
    int t = blockIdx.x * 256 + threadIdx.x;   // 0..4095
    float s = 0.f;
    for (int c = 0; c < NCHUNKS; ++c) s += zpart[(size_t)c * 4096 + t];
    zacc[t] = s;
}

// --------------------------------------------------- lin2 + log_softmax (tiny)
__global__ __launch_bounds__(512)
void k_final(const float* __restrict__ zacc, const float* __restrict__ l1b,
             const float* __restrict__ W2, const float* __restrict__ l2b,
             float* __restrict__ out) {
    __shared__ float r0[512], r1[512];
    int t = threadIdx.x;
    for (int b = 0; b < 8; ++b) {
        float zv = zacc[b * HFC + t] + l1b[t];
        zv = zv > 0.f ? zv : expm1f(zv);
        r0[t] = zv * W2[t * 2 + 0];
        r1[t] = zv * W2[t * 2 + 1];
        __syncthreads();
        for (int s = 256; s; s >>= 1) {
            if (t < s) { r0[t] += r0[t + s]; r1[t] += r1[t + s]; }
            __syncthreads();
        }
        if (t == 0) {
            float o0 = r0[0] + l2b[0], o1 = r1[0] + l2b[1];
            float m = fmaxf(o0, o1);
            float lse = m + logf(expf(o0 - m) + expf(o1 - m));
            out[b * 2 + 0] = o0 - lse;
            out[b * 2 + 1] = o1 - lse;
        }
        __syncthreads();
    }
}

// ---------------------------------------------------------------- launcher
extern "C" void kernel_launch(void* const* d_in, const int* in_sizes, int n_in,
                              void* d_out, int out_size, void* d_ws, size_t ws_size,
                              hipStream_t stream) {
    const float* x    = (const float*)d_in[0];
    const int*   eidx = (const int*)d_in[2];      // [0..E) = row, [E..2E) = col
    const float* gl   = (const float*)d_in[3];
    const float* W1   = (const float*)d_in[4];
    const float* b1   = (const float*)d_in[5];
    const float* W2   = (const float*)d_in[6];
    const float* b2   = (const float*)d_in[7];
    const float* W3   = (const float*)d_in[8];
    const float* b3   = (const float*)d_in[9];
    const float* fcW  = (const float*)d_in[10];
    const float* fcb  = (const float*)d_in[11];
    const float* l1W  = (const float*)d_in[12];
    const float* l1b  = (const float*)d_in[13];
    const float* l2W  = (const float*)d_in[14];
    const float* l2b  = (const float*)d_in[15];
    float* out = (float*)d_out;

    size_t off = 0;
    auto alloc = [&](size_t bytes) {
        void* p = (char*)d_ws + off;
        off += (bytes + 255) & ~(size_t)255;
        return p;
    };
    bf16* bufA          = (bf16*)alloc((size_t)MPAD * 256 * 2);          // 62 MB
    unsigned char* bufC = (unsigned char*)alloc((size_t)MPAD * 256);     // 31 MB
    bf16* W1T      = (bf16*)alloc(256 * K1P * 2);
    bf16* W2T      = (bf16*)alloc(256 * 256 * 2);
    bf16* W3T      = (bf16*)alloc(256 * 256 * 2);
    int*  deg_cnt  = (int*)alloc(NN * 4);
    int*  offs     = (int*)alloc((NN + 1) * 4);
    int*  cursor   = (int*)alloc(NN * 4);
    int*  bsum     = (int*)alloc(SCANB * 4);
    float* dis     = (float*)alloc(NN * 4);
    float* dinv    = (float*)alloc(NN * 4);
    int*  csr_row  = (int*)alloc((size_t)EE * 4);
    float* csr_nrm = (float*)alloc((size_t)EE * 4);
    float* g       = (float*)alloc((size_t)BSZ * NN * 4);

    // zpart/zacc alias bufC: dead after the last k_agg
    float* zpart = (float*)bufC;                              // 3.9 MB
    float* zacc  = (float*)(bufC + (8 << 20));                // 16 KB

    hipMemsetAsync(deg_cnt, 0, NN * 4, stream);
    hipMemsetAsync(g, 0, (size_t)BSZ * NN * 4, stream);

    const int* erow = eidx;
    const int* ecol = eidx + EE;

    k_deg<<<(EE + 255) / 256, 256, 0, stream>>>(ecol, deg_cnt, EE);
    k_scanA<<<SCANB, 256, 0, stream>>>(deg_cnt, cursor, bsum);
    k_scanB<<<1, 64, 0, stream>>>(bsum, offs);
    k_scanC<<<SCANB, 256, 0, stream>>>(deg_cnt, cursor, bsum, offs, dis, dinv);
    k_csr<<<(EE + 255) / 256, 256, 0, stream>>>(erow, ecol, cursor, dis,
                                                csr_row, csr_nrm, EE);

    k_prep_h0<<<(MREAL * (K1P / 8) + 255) / 256, 256, 0, stream>>>(x, gl, bufA);
    k_prep_w<<<(256 * K1P + 255) / 256, 256, 0, stream>>>(W1, W1T, FF + GG, K1P);
    k_prep_w<<<(256 * 256 + 255) / 256, 256, 0, stream>>>(W2, W2T, 256, 256);
    k_prep_w<<<(256 * 256 + 255) / 256, 256, 0, stream>>>(W3, W3T, 256, 256);

    dim3 ggrid(MPAD / 128, 2);

    // layer 1
    k_gemm<K1P><<<ggrid, 256, 0, stream>>>(bufA, W1T, bufC);
    k_agg<<<NN, 128, 0, stream>>>(bufC, bufA, offs, csr_row, csr_nrm, dinv,
                                  b1, fcW + 0, g, 1);
    // layer 2
    k_gemm<256><<<ggrid, 256, 0, stream>>>(bufA, W2T, bufC);
    k_agg<<<NN, 128, 0, stream>>>(bufC, bufA, offs, csr_row, csr_nrm, dinv,
                                  b2, fcW + 1, g, 1);
    // layer 3 (h3 not materialized; only fc contribution)
    k_gemm<256><<<ggrid, 256, 0, stream>>>(bufA, W3T, bufC);
    k_agg<<<NN, 128, 0, stream>>>(bufC, bufA, offs, csr_row, csr_nrm, dinv,
                                  b3, fcW + 2, g, 0);

    k_lin1<<<NCHUNKS, 256, 0, stream>>>(g, fcb, l1W, zpart);
    k_lin1red<<<16, 256, 0, stream>>>(zpart, zacc);
    k_final<<<1, 512, 0, stream>>>(zacc, l1b, l2W, l2b, out);
}